// Round 1
// 848.427 us; speedup vs baseline: 2.5695x; 2.5695x over previous
//
#include <hip/hip_runtime.h>

using bf16x8 = __attribute__((ext_vector_type(8))) __bf16;
using u16x8  = __attribute__((ext_vector_type(8))) unsigned short;
using f32x4  = __attribute__((ext_vector_type(4))) float;

__device__ __forceinline__ unsigned short f2bf(float f){
  unsigned int u = __float_as_uint(f);
  u += 0x7fffu + ((u >> 16) & 1u);     // round-to-nearest-even
  return (unsigned short)(u >> 16);
}
__device__ __forceinline__ float bf2f(unsigned short h){
  return __uint_as_float(((unsigned int)h) << 16);
}

// ---------------- weight fp32 -> bf16 convert ----------------
__global__ __launch_bounds__(256) void cvt_bf16(const float* __restrict__ s,
                                                unsigned short* __restrict__ d, int n){
  int i = blockIdx.x * 256 + threadIdx.x;
  if (i < n) d[i] = f2bf(s[i]);
}

// ---------------- front (amp): h = gelu(LN(x@aW1.T + b1)) ----------------
__global__ __launch_bounds__(256) void front_amp_kernel(
    const float* __restrict__ x,
    const float* __restrict__ W1, const float* __restrict__ b1,
    const float* __restrict__ g1, const float* __restrict__ be1,
    unsigned short* __restrict__ h)
{
  __shared__ float red[256];
  __shared__ float red2[256];
  __shared__ float s_mean, s_inv;
  const int row = blockIdx.x;
  const int tid = threadIdx.x;
  const float x0 = x[row * 2 + 0];
  const float x1 = x[row * 2 + 1];

  float va[16];
  float sum = 0.f, sq = 0.f;
#pragma unroll
  for (int i = 0; i < 16; i++){
    int j = i * 256 + tid;
    float v = x0 * W1[2 * j] + x1 * W1[2 * j + 1] + b1[j];
    va[i] = v; sum += v; sq += v * v;
  }
  red[tid] = sum; red2[tid] = sq; __syncthreads();
  for (int s = 128; s > 0; s >>= 1){
    if (tid < s){ red[tid] += red[tid + s]; red2[tid] += red2[tid + s]; }
    __syncthreads();
  }
  if (tid == 0){
    float m = red[0] * (1.0f / 4096.0f);
    float v = red2[0] * (1.0f / 4096.0f) - m * m;
    s_mean = m; s_inv = rsqrtf(v + 1e-5f);
  }
  __syncthreads();
  float mean = s_mean, inv = s_inv;
#pragma unroll
  for (int i = 0; i < 16; i++){
    int j = i * 256 + tid;
    float y = (va[i] - mean) * inv * g1[j] + be1[j];
    float ge = 0.5f * y * (1.0f + erff(y * 0.70710678118654752f));
    h[(size_t)row * 4096 + j] = f2bf(ge);
  }
}

// ---------------- front (phase): p = silu(LN(x@pW1.T + b1)) ----------------
__global__ __launch_bounds__(256) void front_ph_kernel(
    const float* __restrict__ x,
    const float* __restrict__ W1, const float* __restrict__ b1,
    const float* __restrict__ g1, const float* __restrict__ be1,
    unsigned short* __restrict__ p)
{
  __shared__ float red[256];
  __shared__ float red2[256];
  __shared__ float s_mean, s_inv;
  const int row = blockIdx.x;
  const int tid = threadIdx.x;
  const float x0 = x[row * 2 + 0];
  const float x1 = x[row * 2 + 1];

  float vp[8];
  float sum = 0.f, sq = 0.f;
#pragma unroll
  for (int i = 0; i < 8; i++){
    int j = i * 256 + tid;
    float v = x0 * W1[2 * j] + x1 * W1[2 * j + 1] + b1[j];
    vp[i] = v; sum += v; sq += v * v;
  }
  red[tid] = sum; red2[tid] = sq; __syncthreads();
  for (int s = 128; s > 0; s >>= 1){
    if (tid < s){ red[tid] += red[tid + s]; red2[tid] += red2[tid + s]; }
    __syncthreads();
  }
  if (tid == 0){
    float m = red[0] * (1.0f / 2048.0f);
    float v = red2[0] * (1.0f / 2048.0f) - m * m;
    s_mean = m; s_inv = rsqrtf(v + 1e-5f);
  }
  __syncthreads();
  float mean = s_mean, inv = s_inv;
#pragma unroll
  for (int i = 0; i < 8; i++){
    int j = i * 256 + tid;
    float y = (vp[i] - mean) * inv * g1[j] + be1[j];
    float si = y / (1.0f + expf(-y));
    p[(size_t)row * 2048 + j] = f2bf(si);
  }
}

// ---------------- row-wise LN + tanh, in place on bf16 (N=2048) ----------------
__global__ __launch_bounds__(256) void ln_tanh_kernel(
    unsigned short* __restrict__ c, const float* __restrict__ g,
    const float* __restrict__ be)
{
  __shared__ float red[256];
  __shared__ float red2[256];
  __shared__ float s_mean, s_inv;
  const size_t base = (size_t)blockIdx.x * 2048;
  const int tid = threadIdx.x;
  float v[8];
  float sum = 0.f, sq = 0.f;
#pragma unroll
  for (int i = 0; i < 8; i++){
    int j = i * 256 + tid;
    float t = bf2f(c[base + j]);
    v[i] = t; sum += t; sq += t * t;
  }
  red[tid] = sum; red2[tid] = sq; __syncthreads();
  for (int s = 128; s > 0; s >>= 1){
    if (tid < s){ red[tid] += red[tid + s]; red2[tid] += red2[tid + s]; }
    __syncthreads();
  }
  if (tid == 0){
    float m = red[0] * (1.0f / 2048.0f);
    float vv = red2[0] * (1.0f / 2048.0f) - m * m;
    s_mean = m; s_inv = rsqrtf(vv + 1e-5f);
  }
  __syncthreads();
  float mean = s_mean, inv = s_inv;
#pragma unroll
  for (int i = 0; i < 8; i++){
    int j = i * 256 + tid;
    float y = (v[i] - mean) * inv * g[j] + be[j];
    c[base + j] = f2bf(tanhf(y));
  }
}

// ---------------- bf16 MFMA GEMM: C = A @ B^T (+epilogue) ----------------
// 256x256 block tile, BK=32, 512 thr = 8 waves (4m x 2n), wave = 64x128 out.
//
// R6 counter forensics (748us GEMM1 dispatch):
//   SQ_LDS_BANK_CONFLICT = 6291456 = 512blk*128it*96 ds_read  -> dispatch = GEMM1.
//   WRITE_SIZE 4.29e6 KB = 2x glds demand (2.147GB) + 64MB real output:
//     global_load_lds 64B half-line requests double-count as 128B TCC "writes".
//     NOT HBM store traffic; hbm_gbps/pct_peak derived from it are bogus.
//   Occupancy 23.6% = 8 waves/CU = 1 block/CU (acc 128 AGPR + 96 VGPR regs cap).
//   => old 2-phase loop (stage; compute; __syncthreads -> vmcnt(0) drain) exposed
//      full global->LDS latency every K-step with no co-resident block to hide it.
// This revision:
//   (1) 4-buf LDS pipeline, 3 K-steps in flight, counted vmcnt(8/4/0) + raw
//       s_barrier (T3/T4). 128KB LDS; occupancy unchanged (regs-capped anyway).
//   (2) 16B-unit XOR swizzle (unit ^= (row>>1)&3), applied BOTH-sides: glds
//       global source column pre-swizzled, ds_read address swizzled. Spreads
//       fragment reads over all 8 bank-groups per 16-lane cohort (was 2).
//   (3) bijective XCD-chunked lid swizzle: blocks sharing an A panel land on
//       one XCD's L2 (n-fastest mapping previously round-robined them apart).
//   (4) s_setprio(1) around the MFMA cluster (T5; schedule now role-splits).
// EPI: 0 = bf16(val + bias[col])
//      1 = bf16((sin((val+bias)*rf0+rp0) + ry + tanh(rp2))/3)  [aux2=ry]
//      2 = bf16(cos(tanh(val+bias)*rf1 + rp1))                 [phase ry]
//      3 = f32(val + bias[col])                                [final]

#define WAITV8() asm volatile("s_waitcnt vmcnt(8)" ::: "memory")
#define WAITV4() asm volatile("s_waitcnt vmcnt(4)" ::: "memory")
#define WAITV0() asm volatile("s_waitcnt vmcnt(0)" ::: "memory")

template<int EPI>
__global__ __launch_bounds__(512, 2) void gemm_bt(
    const unsigned short* __restrict__ A, const unsigned short* __restrict__ B,
    void* __restrict__ outp, int M, int N, int K, int nT,
    const float* __restrict__ bias,
    const float* __restrict__ aux0, const float* __restrict__ aux1,
    const unsigned short* __restrict__ aux2)
{
  __shared__ __align__(16) char smem_raw[131072];  // 4 x 32KB staging; epilogue reuses [0,67.6K)
  unsigned short* S = (unsigned short*)smem_raw;

  const int tid  = threadIdx.x;
  const int wave = tid >> 6, lane = tid & 63;
  const int wm = wave >> 1, wn = wave & 1;     // wm 0..3 (64-row band), wn 0..1 (128-col band)
  const int lm = lane & 15, lq = lane >> 4;

  int lid = blockIdx.x;
  {
    const int nwg = gridDim.x;                 // 512 or 256 here: always %8==0
    if ((nwg & 7) == 0) lid = (lid & 7) * (nwg >> 3) + (lid >> 3);
  }
  const int m0 = (lid / nT) * 256, n0 = (lid % nT) * 256;

  f32x4 acc[4][8];
#pragma unroll
  for (int i = 0; i < 4; i++)
#pragma unroll
    for (int j = 0; j < 8; j++) acc[i][j] = (f32x4){0.f, 0.f, 0.f, 0.f};

  // staging: lane i covers row (wave*32 + i/4); the 16B unit it fetches from
  // global is XOR-swizzled by the row so that LDS unit u of row r holds
  // global unit u ^ ((r>>1)&3). glds LDS dest stays linear (HW requirement).
  const int lr = lane >> 2;
  const int lc = (((lane & 3) ^ ((lr >> 1) & 3)) << 3);
  const unsigned short* gA = A + (size_t)(m0 + wave * 32 + lr) * K + lc;
  const unsigned short* gB = B + (size_t)(n0 + wave * 32 + lr) * K + lc;
  const size_t rowK16 = (size_t)16 * K;

  auto stage = [&](int buf){
    unsigned short* lA = S + buf * 16384 + wave * 1024;
    unsigned short* lB = lA + 8192;
    __builtin_amdgcn_global_load_lds(
        (const __attribute__((address_space(1))) void*)gA,
        (__attribute__((address_space(3))) void*)lA, 16, 0, 0);
    __builtin_amdgcn_global_load_lds(
        (const __attribute__((address_space(1))) void*)(gA + rowK16),
        (__attribute__((address_space(3))) void*)(lA + 512), 16, 0, 0);
    __builtin_amdgcn_global_load_lds(
        (const __attribute__((address_space(1))) void*)gB,
        (__attribute__((address_space(3))) void*)lB, 16, 0, 0);
    __builtin_amdgcn_global_load_lds(
        (const __attribute__((address_space(1))) void*)(gB + rowK16),
        (__attribute__((address_space(3))) void*)(lB + 512), 16, 0, 0);
    gA += 32; gB += 32;
  };

  auto compute = [&](int buf){
    const unsigned short* sA = S + buf * 16384;
    const unsigned short* sB = sA + 8192;
    bf16x8 af[4], bfr[8];
#pragma unroll
    for (int t = 0; t < 4; t++){
      const int r = wm * 64 + t * 16 + lm;
      af[t]  = *(const bf16x8*)&sA[r * 32 + ((lq ^ ((r >> 1) & 3)) << 3)];
    }
#pragma unroll
    for (int t = 0; t < 8; t++){
      const int r = wn * 128 + t * 16 + lm;
      bfr[t] = *(const bf16x8*)&sB[r * 32 + ((lq ^ ((r >> 1) & 3)) << 3)];
    }
    __builtin_amdgcn_s_setprio(1);
#pragma unroll
    for (int i = 0; i < 4; i++)
#pragma unroll
      for (int j = 0; j < 8; j++)
        acc[i][j] = __builtin_amdgcn_mfma_f32_16x16x32_bf16(af[i], bfr[j], acc[i][j], 0, 0, 0);
    __builtin_amdgcn_s_setprio(0);
  };

  // ---- K loop: 4 bufs, 3 K-steps in flight, counted vmcnt, raw barriers ----
  // per-wave glds per stage = 4; outstanding at loop top = 12 (steady).
  // vmcnt(8) -> oldest stage (this iter's buf) complete; barrier makes that
  // true for ALL waves' staging of this buf. stage(t+3) overwrites
  // buf[(t-1)&3], whose readers all finished before this barrier.
  const int nTk = K >> 5;
  stage(0); stage(1); stage(2);
  for (int t = 0; t < nTk; ++t){
    if (t + 2 < nTk)      WAITV8();
    else if (t + 1 < nTk) WAITV4();
    else                  WAITV0();
    __builtin_amdgcn_s_barrier();
    if (t + 3 < nTk) stage((t + 3) & 3);
    compute(t & 3);
  }

  // ---- epilogue: per-wave LDS transpose -> coalesced stores ----
  __syncthreads();                 // all waves done reading staging LDS
  float* ew = (float*)smem_raw + wave * 2112;   // 16 rows x stride 132

#pragma unroll
  for (int i = 0; i < 4; i++){
    // phase 1: epilogue math (col params known), write fp32 to private LDS chunk
#pragma unroll
    for (int j = 0; j < 8; j++){
      const int col = n0 + wn * 128 + j * 16 + lm;
      float bcol = bias[col];
      float f0 = 0.f, p0 = 0.f, rzv = 0.f;
      if constexpr (EPI == 1){
        f0 = aux0[3 * col]; p0 = aux1[3 * col]; rzv = tanhf(aux1[3 * col + 2]);
      }
      if constexpr (EPI == 2){
        f0 = aux0[3 * col + 1]; p0 = aux1[3 * col + 1];
      }
#pragma unroll
      for (int r = 0; r < 4; r++){
        const float val = acc[i][j][r];
        float pre;
        if constexpr (EPI == 0 || EPI == 3)      pre = val + bcol;
        else if constexpr (EPI == 1)             pre = sinf((val + bcol) * f0 + p0) + rzv;
        else                                     pre = cosf(tanhf(val + bcol) * f0 + p0);
        ew[(lq * 4 + r) * 132 + j * 16 + lm] = pre;
      }
    }
    // phase 2: read back rows, store coalesced (same wave wrote -> no barrier)
    if constexpr (EPI != 3){
#pragma unroll
      for (int s = 0; s < 4; s++){
        const int lrow = 4 * s + lq;
        const int grow = m0 + wm * 64 + i * 16 + lrow;
        const float* src = ew + lrow * 132 + lm * 8;
        f32x4 v0 = *(const f32x4*)(src);
        f32x4 v1 = *(const f32x4*)(src + 4);
        const size_t gidx = (size_t)grow * N + n0 + wn * 128 + lm * 8;
        u16x8 o;
        if constexpr (EPI == 1){
          u16x8 ry8 = *(const u16x8*)&aux2[gidx];
#pragma unroll
          for (int t = 0; t < 4; t++){
            o[t]     = f2bf((v0[t] + bf2f(ry8[t]))     * (1.0f / 3.0f));
            o[t + 4] = f2bf((v1[t] + bf2f(ry8[t + 4])) * (1.0f / 3.0f));
          }
        } else {
#pragma unroll
          for (int t = 0; t < 4; t++){
            o[t] = f2bf(v0[t]); o[t + 4] = f2bf(v1[t]);
          }
        }
        *(u16x8*)&((unsigned short*)outp)[gidx] = o;
      }
    } else {
#pragma unroll
      for (int s = 0; s < 8; s++){
        const int lrow = 2 * s + (lane >> 5);
        const int grow = m0 + wm * 64 + i * 16 + lrow;
        const int lcol = (lane & 31) * 4;
        f32x4 v = *(const f32x4*)(ew + lrow * 132 + lcol);
        *(f32x4*)&((float*)outp)[(size_t)grow * N + n0 + wn * 128 + lcol] = v;
      }
    }
  }
}

extern "C" void kernel_launch(void* const* d_in, const int* in_sizes, int n_in,
                              void* d_out, int out_size, void* d_ws, size_t ws_size,
                              hipStream_t stream)
{
  const float* x    = (const float*)d_in[0];
  const float* aW1  = (const float*)d_in[1];
  const float* ab1  = (const float*)d_in[2];
  const float* ag1  = (const float*)d_in[3];
  const float* abe1 = (const float*)d_in[4];
  const float* aW2  = (const float*)d_in[5];
  const float* ab2  = (const float*)d_in[6];
  const float* ag2  = (const float*)d_in[7];
  const float* abe2 = (const float*)d_in[8];
  const float* aW3  = (const float*)d_in[9];
  const float* ab3  = (const float*)d_in[10];
  const float* pW1  = (const float*)d_in[11];
  const float* pb1  = (const float*)d_in[12];
  const float* pg1  = (const float*)d_in[13];
  const float* pbe1 = (const float*)d_in[14];
  const float* pW2  = (const float*)d_in[15];
  const float* pb2  = (const float*)d_in[16];
  const float* rfreq  = (const float*)d_in[17];
  const float* rphase = (const float*)d_in[18];
  const float* aiw  = (const float*)d_in[19];
  const float* aib  = (const float*)d_in[20];
  const float* aow  = (const float*)d_in[21];
  const float* aob  = (const float*)d_in[22];

  const int B = 16384, Q = 1024;

  // ---- workspace layout (~188 MB; c2 lives in d_out) ----
  char* ws = (char*)d_ws;
  size_t off = 0;
  auto alloc = [&](size_t bytes) -> char* {
    char* ptr = ws + off; off += (bytes + 255) & ~(size_t)255; return ptr;
  };
  unsigned short* Wb2  = (unsigned short*)alloc((size_t)2 * Q * 4 * Q * 2); // 16 MB
  unsigned short* Wb3  = (unsigned short*)alloc((size_t)Q * 2 * Q * 2);     //  4 MB
  unsigned short* PWb2 = (unsigned short*)alloc((size_t)Q * 2 * Q * 2);     //  4 MB
  unsigned short* WVb  = (unsigned short*)alloc((size_t)Q * Q * 2);         //  2 MB
  unsigned short* WOb  = (unsigned short*)alloc((size_t)Q * Q * 2);         //  2 MB
  unsigned short* R1   = (unsigned short*)alloc((size_t)B * 4 * Q * 2);     // 128 MB shared region
  unsigned short* ry   = (unsigned short*)alloc((size_t)B * Q * 2);         //  32 MB

  // R1 overlays (time-disjoint):
  unsigned short* p  = R1;                      // phase act (dead after gemm_ph)
  unsigned short* h  = R1;                      // amp act   (dead after gemm1)
  unsigned short* qs = R1;                      // combine out (after h dead)
  unsigned short* v  = R1 + (size_t)B * Q;      // v (after h dead)
  unsigned short* c2 = (unsigned short*)d_out;  // borrow output buffer (64 MB), dead before final GEMM

  // weight converts (bf16)
  cvt_bf16<<<(2*Q*4*Q + 255) / 256, 256, 0, stream>>>(aW2, Wb2, 2*Q*4*Q);
  cvt_bf16<<<(Q*2*Q + 255) / 256, 256, 0, stream>>>(aW3, Wb3, Q*2*Q);
  cvt_bf16<<<(Q*2*Q + 255) / 256, 256, 0, stream>>>(pW2, PWb2, Q*2*Q);
  cvt_bf16<<<(Q*Q + 255) / 256, 256, 0, stream>>>(aiw + (size_t)2*Q*Q, WVb, Q*Q);
  cvt_bf16<<<(Q*Q + 255) / 256, 256, 0, stream>>>(aow, WOb, Q*Q);

  const float* rf4 = rfreq  + (size_t)4 * Q * 3;   // rot_freq[-1]
  const float* rp4 = rphase + (size_t)4 * Q * 3;   // rot_phase[-1]

  const int mT = B / 256;          // 64
  const int nT1 = 2 * Q / 256;     // 8
  const int nTq = Q / 256;         // 4

  // ---- phase path first (so p's region can be reused by h) ----
  front_ph_kernel<<<B, 256, 0, stream>>>(x, pW1, pb1, pg1, pbe1, p);
  // ry = cos(tanh(p@pW2.T + pb2)*rf1 + rp1)   (N=1024, K=2048)
  gemm_bt<2><<<nTq * mT, 512, 0, stream>>>(p, PWb2, ry, B, Q, 2*Q, nTq,
                                           pb2, rf4, rp4, nullptr);

  // ---- amp path ----
  front_amp_kernel<<<B, 256, 0, stream>>>(x, aW1, ab1, ag1, abe1, h);
  // GEMM1: c2 = h @ aW2.T + b2   (M=16384, N=2048, K=4096), bf16 out (in d_out)
  gemm_bt<0><<<nT1 * mT, 512, 0, stream>>>(h, Wb2, c2, B, 2*Q, 4*Q, nT1,
                                           ab2, nullptr, nullptr, nullptr);
  // h2 = tanh(LN(c2)) in place
  ln_tanh_kernel<<<B, 256, 0, stream>>>(c2, ag2, abe2);

  // GEMM2 (fused combine): qs = (sin((c2h@aW3.T+b3)*rf0+rp0) + ry + tanh(rp2))/3
  gemm_bt<1><<<nTq * mT, 512, 0, stream>>>(c2, Wb3, qs, B, Q, 2*Q, nTq,
                                           ab3, rf4, rp4, ry);
  // GEMM4: v = qs @ aiw[2Q:].T + aib[2Q:]   (N=1024, K=1024)
  gemm_bt<0><<<nTq * mT, 512, 0, stream>>>(qs, WVb, v, B, Q, Q, nTq,
                                           aib + 2*Q, nullptr, nullptr, nullptr);
  // GEMM5: out = v @ aow.T + aob   (N=1024, K=1024), fp32 out (overwrites dead c2)
  gemm_bt<3><<<nTq * mT, 512, 0, stream>>>(v, WOb, d_out, B, Q, Q, nTq,
                                           aob, nullptr, nullptr, nullptr);
}